// Round 9
// baseline (2287.114 us; speedup 1.0000x reference)
//
#include <hip/hip_runtime.h>

#define N_ITER 20
#define ALPHA 0.01f

typedef unsigned short ushort_t;
typedef __attribute__((ext_vector_type(8))) short bf16x8;
typedef __attribute__((ext_vector_type(16))) float f32x16;

__device__ __forceinline__ float csign(int a, int b) {
    int s = 0;
    for (int aa = a >> 1; aa; aa >>= 1) s += __popc(aa & b);
    return (s & 1) ? -1.0f : 1.0f;
}

__device__ __forceinline__ float revsign(int b) {
    int k = __popc(b);
    return ((k * (k - 1) / 2) & 1) ? -1.0f : 1.0f;
}

__device__ __forceinline__ ushort_t f2bf(float f) {
    union { float f; unsigned u; } v;
    v.f = f;
    unsigned r = v.u + 0x7fffu + ((v.u >> 16) & 1u);  // RNE; inputs finite
    return (ushort_t)(r >> 16);
}

// Swizzled storage for logical (r, k) in an [R][K] bf16 operand buffer.
// Within each 64-elem k-group (128 B), 16B block j lives at j ^ (r&7).
// Verbatim LDS staging; fragment ds_read_b128 layout (verified rounds 1-8).
__device__ __forceinline__ size_t swz64(int r, int k, int K) {
    return (size_t)r * K + (k & ~63) + ((((k >> 3) ^ r) & 7) << 3) + (k & 7);
}

__device__ __forceinline__ void async16(const void* g, void* l) {
    __builtin_amdgcn_global_load_lds((const __attribute__((address_space(1))) void*)g,
                                     (__attribute__((address_space(3))) void*)l, 16, 0, 0);
}

template <int N>
__device__ __forceinline__ void waitcnt_vm() {
    if constexpr (N == 0) asm volatile("s_waitcnt vmcnt(0)" ::: "memory");
    else if constexpr (N == 4) asm volatile("s_waitcnt vmcnt(4)" ::: "memory");
    else if constexpr (N == 6) asm volatile("s_waitcnt vmcnt(6)" ::: "memory");
    else if constexpr (N == 8) asm volatile("s_waitcnt vmcnt(8)" ::: "memory");
    else asm volatile("s_waitcnt vmcnt(0)" ::: "memory");
}

// Build bf16 swz64 GP matrices from W [P, Q, 8]:
//  MfA    [Q8][P8]: forward GP, A-layout    MfA[q8+a][p8+c]    = s*w
//  Mrbt   [Q8][P8]: reverse GP, B^T layout  Mrbt[q8+c][p8+a]   = s*rev*w
//  Mrneg  [Q8][P8]: -Mrbt
//  Mbtneg [P8][Q8]: -forward GP, B^T layout Mbtneg[p8+c][q8+a] = -s*w
__global__ void build_M_kernel(const float* __restrict__ W, ushort_t* __restrict__ MfA,
                               ushort_t* __restrict__ Mrbt, ushort_t* __restrict__ Mrneg,
                               ushort_t* __restrict__ Mbtneg, int P, int Q) {
    int idx = blockIdx.x * blockDim.x + threadIdx.x;
    int total = P * Q * 64;
    if (idx >= total) return;
    int c = idx & 7;
    int a = (idx >> 3) & 7;
    int pq = idx >> 6;
    int q = pq % Q;
    int p = pq / Q;
    int b = a ^ c;
    float w = W[((size_t)p * Q + q) * 8 + b];
    float fw = csign(a, b) * w;
    float rw = csign(a, b) * revsign(b) * w;
    MfA[swz64(q * 8 + a, p * 8 + c, P * 8)] = f2bf(fw);
    Mrbt[swz64(q * 8 + c, p * 8 + a, P * 8)] = f2bf(rw);
    if (Mrneg) Mrneg[swz64(q * 8 + c, p * 8 + a, P * 8)] = f2bf(-rw);
    if (Mbtneg) Mbtneg[swz64(p * 8 + c, q * 8 + a, Q * 8)] = f2bf(-fw);
}

// fp32 [R][K] plain -> bf16 swz64
__global__ void f2bf_swz_kernel(const float* __restrict__ in, ushort_t* __restrict__ out,
                                int n, int kshift) {
    int i = blockIdx.x * blockDim.x + threadIdx.x;
    if (i >= n) return;
    int K = 1 << kshift;
    int r = i >> kshift;
    int k = i & (K - 1);
    out[swz64(r, k, K)] = f2bf(in[i]);
}

// Pipelined MFMA accumulation core (round-4/6 verified). BMxBN tile, BK=64,
// 256 threads (4 waves 2x2), wave tile (BM/2)x(BN/2). Triple-buffered LDS,
// 2-chunk-ahead global_load_lds prefetch, counted vmcnt (never 0 mid-loop),
// one raw s_barrier per chunk. Two K-phases unified into one chunk sequence.
template <int BM, int BN>
__device__ __forceinline__ void gemm_core(f32x16 (&acc)[BM / 64][BN / 64],
                                          ushort_t* __restrict__ S,
                                          const ushort_t* __restrict__ A,
                                          const ushort_t* __restrict__ BT, int K,
                                          const ushort_t* __restrict__ A2,
                                          const ushort_t* __restrict__ BT2, int K2,
                                          int row0, int col0) {
    constexpr int FI = BM / 64;
    constexpr int FJ = BN / 64;
    constexpr int CPW = (BM + BN) / 32;
    constexpr int SZ = (BM + BN) * 64;

    const int t = threadIdx.x;
    const int lane = t & 63;
    const int w = t >> 6;
    const int wr = w >> 1;
    const int wc = w & 1;
    const int l31 = lane & 31;
    const int lh = lane >> 5;
    const int srow = lane >> 3;
    const int sk = (lane & 7) * 8;
    const int sw7 = l31 & 7;

#pragma unroll
    for (int i = 0; i < FI; ++i)
#pragma unroll
        for (int j = 0; j < FJ; ++j)
#pragma unroll
            for (int r = 0; r < 16; ++r) acc[i][j][r] = 0.0f;

    const ushort_t* gpA[CPW];
    const ushort_t* gpB[CPW];
    int lofs[CPW];
#pragma unroll
    for (int cc = 0; cc < CPW; ++cc) {
        int ch = cc * 4 + w;
        int r8 = ch * 8;
        lofs[cc] = ch * 512;
        if (r8 < BM) {
            gpA[cc] = A + (size_t)(row0 + r8 + srow) * K + sk;
            gpB[cc] = A2 ? (A2 + (size_t)(row0 + r8 + srow) * K2 + sk) : A;
        } else {
            gpA[cc] = BT + (size_t)(col0 + r8 - BM + srow) * K + sk;
            gpB[cc] = BT2 ? (BT2 + (size_t)(col0 + r8 - BM + srow) * K2 + sk) : BT;
        }
    }

    const int T1 = K >> 6;
    const int T2 = K2 >> 6;
    const int Ttot = T1 + T2;

    auto stage = [&](int tt, ushort_t* Sb) {
        if (tt < T1) {
#pragma unroll
            for (int cc = 0; cc < CPW; ++cc)
                async16(gpA[cc] + (size_t)tt * 64, &Sb[lofs[cc]]);
        } else {
            const int tl = tt - T1;
#pragma unroll
            for (int cc = 0; cc < CPW; ++cc)
                async16(gpB[cc] + (size_t)tl * 64, &Sb[lofs[cc]]);
        }
    };

    ushort_t* B0 = S;
    ushort_t* B1 = S + SZ;
    ushort_t* B2 = S + 2 * SZ;
    stage(0, B0);
    if (Ttot > 1) stage(1, B1);

    for (int tt = 0; tt < Ttot; ++tt) {
        if (tt + 1 < Ttot) {
            waitcnt_vm<CPW>();
        } else {
            waitcnt_vm<0>();
        }
        __builtin_amdgcn_s_barrier();
        __builtin_amdgcn_sched_barrier(0);

        if (tt + 2 < Ttot) stage(tt + 2, B2);

        bf16x8 af[4][FI], bfm[4][FJ];
#pragma unroll
        for (int s = 0; s < 4; ++s) {
            int pos = ((2 * s + lh) ^ sw7) * 8;
#pragma unroll
            for (int i = 0; i < FI; ++i)
                af[s][i] = *(const bf16x8*)&B0[(wr * (BM / 2) + i * 32 + l31) * 64 + pos];
#pragma unroll
            for (int j = 0; j < FJ; ++j)
                bfm[s][j] = *(const bf16x8*)&B0[(BM + wc * (BN / 2) + j * 32 + l31) * 64 + pos];
        }
#pragma unroll
        for (int s = 0; s < 4; ++s)
#pragma unroll
            for (int i = 0; i < FI; ++i)
#pragma unroll
                for (int j = 0; j < FJ; ++j)
                    acc[i][j] = __builtin_amdgcn_mfma_f32_32x32x16_bf16(af[s][i], bfm[s][j],
                                                                        acc[i][j], 0, 0, 0);
        ushort_t* tmp = B0; B0 = B1; B1 = B2; B2 = tmp;
    }
}

// Standalone GEMM (precompute only), with XCD swizzle (1-D grid, ypx = GY/8).
// MODE 1: Fout fp32 = acc                                       (R precompute)
// MODE 4: Bout[swz64(col,row,N)] = bf16(acc + (ADDI && row==col))  (GmT build)
template <int MODE, int BM, int BN, bool ADDI>
__global__ __launch_bounds__(256) void gemm_k(const ushort_t* __restrict__ A,
                                              const ushort_t* __restrict__ BT, int K,
                                              ushort_t* __restrict__ Bout,
                                              float* __restrict__ Fout, int N, int ypx) {
    __shared__ ushort_t S[3 * (BM + BN) * 64];
    const int wg = blockIdx.x;
    const int xcd = wg & 7;
    const int idx = wg >> 3;
    const int by = xcd * ypx + idx % ypx;
    const int bx = idx / ypx;

    f32x16 acc[BM / 64][BN / 64];
    gemm_core<BM, BN>(acc, S, A, BT, K, nullptr, nullptr, 0, by * BM, bx * BN);

    const int lane = threadIdx.x & 63;
    const int w = threadIdx.x >> 6;
    const int wr = w >> 1;
    const int wc = w & 1;
    const int l31 = lane & 31;
    const int lh = lane >> 5;
    const int row0 = by * BM;
    const int col0 = bx * BN;

#pragma unroll
    for (int i = 0; i < BM / 64; ++i) {
#pragma unroll
        for (int j = 0; j < BN / 64; ++j) {
#pragma unroll
            for (int r = 0; r < 16; ++r) {
                int row = row0 + wr * (BM / 2) + i * 32 + (r & 3) + 8 * (r >> 2) + 4 * lh;
                int col = col0 + wc * (BN / 2) + j * 32 + l31;
                float v = acc[i][j][r];
                if (MODE == 1) {
                    Fout[(size_t)row * N + col] = v;
                } else {  // MODE 4 (square matrix output)
                    float vv = v + ((ADDI && row == col) ? 1.0f : 0.0f);
                    Bout[swz64(col, row, N)] = f2bf(vv);
                }
            }
        }
    }
}

// ---- Grid-wide barrier (plain launch; no cooperative API) ----
// Monotonic 2-level counters in workspace (zeroed per replay by memsetAsync).
// bar[g*32], g=0..7: per-group arrival counts (groups of 64 blocks, 128B apart)
// bar[8*32]: top counter; bar[9*32]: release (== number of completed barriers).
// Leader: device-scope release fence -> arrive; last-of-group bumps top;
// last-of-top bumps release. All leaders spin (atomic read, s_sleep backoff),
// then acquire fence (invalidates this CU's L1 + XCD L2 on gfx940+).
__device__ __forceinline__ void grid_bar(unsigned* bar, unsigned k, int b) {
    __syncthreads();
    if (threadIdx.x == 0) {
        __threadfence();                       // release: block's stores -> visible
        unsigned old = atomicAdd(&bar[(b >> 6) * 32], 1u);
        if (old == 64u * k - 1u) {
            unsigned ot = atomicAdd(&bar[8 * 32], 1u);
            if (ot == 8u * k - 1u) atomicAdd(&bar[9 * 32], 1u);
        }
        while (atomicAdd(&bar[9 * 32], 0u) < k) __builtin_amdgcn_s_sleep(1);
        __threadfence();                       // acquire: drop stale cached lines
    }
    __syncthreads();
}

// Persistent kernel: the whole 20-iteration PC loop in ONE plain dispatch.
// 512 blocks x 256 threads, 2 blocks/CU (72KB LDS, <=256 VGPR). Block b owns
// (XCD-aligned: blockIdx->XCD round-robins b&7, so both tiles' rows live in
// XCD (b&7)'s L2 across the whole run):
//   A-tile: H1 rows byA*128, cols bxA*64;  byA=(b&7)*4+((b>>3)&3), bxA=b>>5
//   B-tile: H2 rows byB*64,  cols bxB*64;  byB=(b&7)*8+((b>>3)&7), bxB=b>>6
// fp32 state (H1,R,H2 tiles) lives in registers for all 20 iterations; bf16
// swz64 buffers are the only inter-block traffic. Numerics of bf16-carried
// state verified in rounds 7/8 (absmax 0.0039 vs threshold 0.108).
__global__ __launch_bounds__(256, 2) void pc_iter_kernel(
    const ushort_t* __restrict__ GmT1p, const ushort_t* __restrict__ M2btneg,
    const ushort_t* __restrict__ GmT2, const ushort_t* __restrict__ M2rneg,
    ushort_t* __restrict__ H1b0, ushort_t* __restrict__ H1b1,
    ushort_t* __restrict__ H2b0, ushort_t* __restrict__ H2b1,
    const float* __restrict__ Rp, const float* __restrict__ h1in,
    const float* __restrict__ h2in, float* __restrict__ H1out,
    float* __restrict__ H2out, unsigned* bar) {
    __shared__ ushort_t S[3 * (128 + 64) * 64];  // 72 KB (A-phase; B uses prefix)

    const int b = blockIdx.x;
    const int lane = threadIdx.x & 63;
    const int w = threadIdx.x >> 6;
    const int wr = w >> 1;
    const int wc = w & 1;
    const int l31 = lane & 31;
    const int lh = lane >> 5;

    const int rowA = ((b & 7) * 4 + ((b >> 3) & 3)) * 128;
    const int colA = (b >> 5) * 64;
    const int rowB = ((b & 7) * 8 + ((b >> 3) & 7)) * 64;
    const int colB = (b >> 6) * 64;

    // Persistent fp32 state tiles in registers (acc-layout indexing).
    float h1reg[2][16], rreg[2][16], h2reg[16];
#pragma unroll
    for (int i = 0; i < 2; ++i)
#pragma unroll
        for (int r = 0; r < 16; ++r) {
            int row = rowA + wr * 64 + i * 32 + (r & 3) + 8 * (r >> 2) + 4 * lh;
            int col = colA + wc * 32 + l31;
            size_t off = (size_t)row * 1024 + col;
            h1reg[i][r] = h1in[off];
            rreg[i][r] = Rp[off];
        }
#pragma unroll
    for (int r = 0; r < 16; ++r) {
        int row = rowB + wr * 32 + (r & 3) + 8 * (r >> 2) + 4 * lh;
        int col = colB + wc * 32 + l31;
        h2reg[r] = h2in[(size_t)row * 512 + col];
    }

    ushort_t* h1rd = H1b0; ushort_t* h1wr = H1b1;
    ushort_t* h2rd = H2b0; ushort_t* h2wr = H2b1;

    unsigned k = 0;
    for (int it = 0; it < N_ITER; ++it) {
        // Phase A: acc = H1old@Gm1pT + H2old@(-M2bt); H1 <- H1 - a*clip(acc - R)
        {
            f32x16 acc[2][1];
            gemm_core<128, 64>(acc, S, h1rd, GmT1p, 1024, h2rd, M2btneg, 512, rowA, colA);
#pragma unroll
            for (int i = 0; i < 2; ++i)
#pragma unroll
                for (int r = 0; r < 16; ++r) {
                    int row = rowA + wr * 64 + i * 32 + (r & 3) + 8 * (r >> 2) + 4 * lh;
                    int col = colA + wc * 32 + l31;
                    float g = fminf(fmaxf(acc[i][0][r] - rreg[i][r], -1.0f), 1.0f);
                    h1reg[i][r] -= ALPHA * g;
                    h1wr[swz64(row, col, 1024)] = f2bf(h1reg[i][r]);
                    if (it == N_ITER - 1) H1out[(size_t)row * 1024 + col] = h1reg[i][r];
                }
        }
        grid_bar(bar, ++k, b);

        // Phase B: acc = H2old@Gm2T + H1new@(-M2r); H2 <- H2 - a*clip(acc)
        {
            f32x16 acc[1][1];
            gemm_core<64, 64>(acc, S, h2rd, GmT2, 512, h1wr, M2rneg, 1024, rowB, colB);
#pragma unroll
            for (int r = 0; r < 16; ++r) {
                int row = rowB + wr * 32 + (r & 3) + 8 * (r >> 2) + 4 * lh;
                int col = colB + wc * 32 + l31;
                float g = fminf(fmaxf(acc[0][0][r], -1.0f), 1.0f);
                h2reg[r] -= ALPHA * g;
                h2wr[swz64(row, col, 512)] = f2bf(h2reg[r]);
                if (it == N_ITER - 1) H2out[(size_t)row * 512 + col] = h2reg[r];
            }
        }
        grid_bar(bar, ++k, b);

        ushort_t* tmp;
        tmp = h1rd; h1rd = h1wr; h1wr = tmp;
        tmp = h2rd; h2rd = h2wr; h2wr = tmp;
    }
}

extern "C" void kernel_launch(void* const* d_in, const int* in_sizes, int n_in,
                              void* d_out, int out_size, void* d_ws, size_t ws_size,
                              hipStream_t stream) {
    const float* X  = (const float*)d_in[0];  // [4096, 256, 8]
    const float* W1 = (const float*)d_in[1];  // [256, 128, 8]
    const float* W2 = (const float*)d_in[2];  // [128, 64, 8]
    const float* h1 = (const float*)d_in[3];  // [4096, 128, 8]
    const float* h2 = (const float*)d_in[4];  // [4096, 64, 8]
    float* out = (float*)d_out;

    const size_t szX  = (size_t)4096 * 2048;
    const size_t szH1 = (size_t)4096 * 1024;
    const size_t szH2 = (size_t)4096 * 512;

    float* outX = out;
    float* H1 = out + szX;
    float* H2 = H1 + szH1;

    // workspace (~94 MB of ~268 MB)
    ushort_t* M1fwdA  = (ushort_t*)d_ws;                 // [1024][2048]
    ushort_t* M1rbt   = M1fwdA + (size_t)1024 * 2048;    // [1024][2048]
    ushort_t* M2fwdA  = M1rbt + (size_t)1024 * 2048;     // [512][1024]
    ushort_t* M2rbt   = M2fwdA + (size_t)512 * 1024;     // [512][1024]
    ushort_t* M2rneg  = M2rbt + (size_t)512 * 1024;      // [512][1024]
    ushort_t* M2btneg = M2rneg + (size_t)512 * 1024;     // [1024][512]
    ushort_t* GmT1p   = M2btneg + (size_t)1024 * 512;    // [1024][1024]
    ushort_t* GmT2    = GmT1p + (size_t)1024 * 1024;     // [512][512]
    ushort_t* Xb      = GmT2 + (size_t)512 * 512;        // [4096][2048]
    ushort_t* H1bA    = Xb + szX;                        // [4096][1024]
    ushort_t* H1bB    = H1bA + szH1;
    ushort_t* H2bA    = H1bB + szH1;                     // [4096][512]
    ushort_t* H2bB    = H2bA + szH2;
    float*    R       = (float*)(H2bB + szH2);           // [4096][1024] fp32
    unsigned* bar     = (unsigned*)(R + szH1);           // barrier counters (5 KB)

    hipMemsetAsync(bar, 0, 40 * 32 * sizeof(unsigned), stream);

    build_M_kernel<<<(256 * 128 * 64 + 255) / 256, 256, 0, stream>>>(
        W1, M1fwdA, M1rbt, nullptr, nullptr, 256, 128);
    build_M_kernel<<<(128 * 64 * 64 + 255) / 256, 256, 0, stream>>>(
        W2, M2fwdA, M2rbt, M2rneg, M2btneg, 128, 64);

    f2bf_swz_kernel<<<(int)((szX + 255) / 256), 256, 0, stream>>>(X, Xb, (int)szX, 11);
    f2bf_swz_kernel<<<(int)((szH1 + 255) / 256), 256, 0, stream>>>(h1, H1bA, (int)szH1, 10);
    f2bf_swz_kernel<<<(int)((szH2 + 255) / 256), 256, 0, stream>>>(h2, H2bA, (int)szH2, 9);

    // Precompute R = X@M1r (fp32), GmT1p = (M1@M1r + I)^T, GmT2 = (M2@M2r)^T
    gemm_k<1, 128, 64, false><<<dim3(16 * 32), 256, 0, stream>>>(
        Xb, M1rbt, 2048, nullptr, R, 1024, 4);
    gemm_k<4, 128, 64, true><<<dim3(16 * 8), 256, 0, stream>>>(
        M1fwdA, M1rbt, 2048, GmT1p, nullptr, 1024, 1);
    gemm_k<4, 64, 64, false><<<dim3(8 * 8), 256, 0, stream>>>(
        M2fwdA, M2rbt, 1024, GmT2, nullptr, 512, 1);

    // Whole 20-iteration loop: one persistent dispatch (plain launch; graph-safe).
    pc_iter_kernel<<<dim3(512), dim3(256), 0, stream>>>(
        GmT1p, M2btneg, GmT2, M2rneg, H1bA, H1bB, H2bA, H2bB, R, h1, h2, H1, H2, bar);

    // x passes through unchanged
    hipMemcpyAsync(outX, X, szX * sizeof(float), hipMemcpyDeviceToDevice, stream);
}